// Round 5
// baseline (1230.590 us; speedup 1.0000x reference)
//
#include <hip/hip_runtime.h>

// Problem constants (fixed by the reference's setup_inputs)
#define BATCH   256
#define N_PER   4096
#define EMBED   16
#define HID     32
#define NOTE    64
#define LSTM_D  64
#define T_LEN   128
#define VOCAB   200

// ---------------------------------------------------------------------------
// meta header (ints)
#define MH_C0    0     // kind-0 leaf count (per tree)
#define MH_C1    1     // kind-1 ptr count
#define MH_CNT   2     // [2..6] internal count at level 1..5
#define MH_P     7     // total parents (internal levels 1..5 + root)
#define MH_PBASE 8     // [8..12] pidx base of level 1..5
// arrays
#define OFF_K0N   64
#define OFF_K0S   (OFF_K0N + N_PER)
#define OFF_K1N   (OFF_K0S + N_PER)
#define OFF_K1S   (OFF_K1N + N_PER)
#define OFF_PLIST (OFF_K1S + N_PER)
#define OFF_WSLOT (OFF_PLIST + N_PER)
#define OFF_COFF  (OFF_WSLOT + N_PER)    // N_PER+1 entries
// float regions (byte offsets in ws)
#define PTRPRE_OFF (2ull * 1024 * 1024)  // [BATCH][T_LEN][HID]
#define H_OFF      (8ull * 1024 * 1024)  // [BATCH][N_PER][HID] slot-indexed

// ---------------------------------------------------------------------------
// Build: bucket nodes (k0 leaves, k1 ptr, levels 1..5, root) with stable
// packed-u64 scans; parents ordered by level; slots = CSR position in the
// parent's children block (so each level's gather range is contiguous).
// ---------------------------------------------------------------------------
__global__ __launch_bounds__(1024) void build_structure(
    const int* __restrict__ kind, const int* __restrict__ height,
    const int* __restrict__ parent, int* __restrict__ meta)
{
    __shared__ unsigned long long p64[1024];
    __shared__ int pint[1024];
    __shared__ int node2pidx[N_PER];   // 16 KB
    __shared__ int deg[N_PER];         // 16 KB
    __shared__ int sbases[8];
    __shared__ int stot[8];

    int t  = threadIdx.x;
    int i0 = 4 * t;

    int myb[4];
    #pragma unroll
    for (int q = 0; q < 4; ++q) {
        int i = i0 + q;
        int hgt = height[i];
        int b;
        if (hgt > 0) { b = 1 + hgt; if (b > 7) b = 7; }   // levels 1..5 -> 2..6, root -> 7
        else b = (kind[i] == 0) ? 0 : 1;
        myb[q] = b;
    }
    unsigned long long clo = 0, chi = 0;
    #pragma unroll
    for (int q = 0; q < 4; ++q) {
        int b = myb[q];
        if (b < 4) clo += 1ull << (16 * b);
        else       chi += 1ull << (16 * (b - 4));
    }
    // scan lo (Hillis-Steele, inclusive)
    p64[t] = clo; __syncthreads();
    for (int off = 1; off < 1024; off <<= 1) {
        unsigned long long v = (t >= off) ? p64[t - off] : 0ull; __syncthreads();
        p64[t] += v; __syncthreads();
    }
    unsigned long long inc_lo = p64[t];
    if (t == 1023) {
        stot[0] = (int)(inc_lo & 0xFFFF);         stot[1] = (int)((inc_lo >> 16) & 0xFFFF);
        stot[2] = (int)((inc_lo >> 32) & 0xFFFF); stot[3] = (int)((inc_lo >> 48) & 0xFFFF);
    }
    __syncthreads();
    // scan hi
    p64[t] = chi; __syncthreads();
    for (int off = 1; off < 1024; off <<= 1) {
        unsigned long long v = (t >= off) ? p64[t - off] : 0ull; __syncthreads();
        p64[t] += v; __syncthreads();
    }
    unsigned long long inc_hi = p64[t];
    if (t == 1023) {
        stot[4] = (int)(inc_hi & 0xFFFF);         stot[5] = (int)((inc_hi >> 16) & 0xFFFF);
        stot[6] = (int)((inc_hi >> 32) & 0xFFFF); stot[7] = (int)((inc_hi >> 48) & 0xFFFF);
    }
    __syncthreads();
    if (t == 0) {
        int s = 0;
        for (int b = 0; b < 8; ++b) { sbases[b] = s; s += stot[b]; }
        meta[MH_C0] = stot[0];
        meta[MH_C1] = stot[1];
        for (int l = 0; l < 5; ++l) meta[MH_CNT + l]   = stot[2 + l];
        for (int l = 0; l < 5; ++l) meta[MH_PBASE + l] = sbases[2 + l] - sbases[2];
        meta[MH_P] = (sbases[7] - sbases[2]) + stot[7];
    }
    __syncthreads();

    unsigned long long exlo = inc_lo - clo, exhi = inc_hi - chi;
    int mypos[4], mypidx[4];
    #pragma unroll
    for (int q = 0; q < 4; ++q) {
        int i = i0 + q, b = myb[q];
        int pos;
        if (b < 4) { pos = (int)((exlo >> (16 * b)) & 0xFFFF); exlo += 1ull << (16 * b); }
        else       { pos = (int)((exhi >> (16 * (b - 4))) & 0xFFFF); exhi += 1ull << (16 * (b - 4)); }
        mypos[q] = pos;
        int pidx = -1;
        if (b == 0)      meta[OFF_K0N + pos] = i;
        else if (b == 1) meta[OFF_K1N + pos] = i;
        else {
            pidx = (sbases[b] - sbases[2]) + pos;
            meta[OFF_PLIST + pidx] = i;
            node2pidx[i] = pidx;
        }
        mypidx[q] = pidx;
    }
    #pragma unroll
    for (int q = 0; q < 4; ++q) deg[i0 + q] = 0;
    __syncthreads();

    int par[4];
    #pragma unroll
    for (int q = 0; q < 4; ++q) {
        int i = i0 + q; par[q] = parent[i];
        if (i != 0) atomicAdd(&deg[node2pidx[par[q]]], 1);
    }
    __syncthreads();

    // exclusive prefix over deg[4096] (pidx-indexed, zero-padded past P)
    int d0 = deg[i0], d1 = deg[i0 + 1], d2 = deg[i0 + 2], d3 = deg[i0 + 3];
    int s4 = d0 + d1 + d2 + d3;
    pint[t] = s4; __syncthreads();
    for (int off = 1; off < 1024; off <<= 1) {
        int v = (t >= off) ? pint[t - off] : 0; __syncthreads();
        pint[t] += v; __syncthreads();
    }
    int ex = pint[t] - s4;
    int o0 = ex, o1 = ex + d0, o2 = o1 + d1, o3 = o2 + d2;
    deg[i0] = o0; deg[i0 + 1] = o1; deg[i0 + 2] = o2; deg[i0 + 3] = o3;
    meta[OFF_COFF + i0]     = o0;
    meta[OFF_COFF + i0 + 1] = o1;
    meta[OFF_COFF + i0 + 2] = o2;
    meta[OFF_COFF + i0 + 3] = o3;
    if (t == 1023) meta[OFF_COFF + N_PER] = o3 + d3;
    __syncthreads();

    // slot = CSR position inside parent's children block (deg[] as cursor)
    #pragma unroll
    for (int q = 0; q < 4; ++q) {
        int i = i0 + q; if (i == 0) continue;
        int slot = atomicAdd(&deg[node2pidx[par[q]]], 1);
        int b = myb[q];
        if (b == 0)      meta[OFF_K0S + mypos[q]] = slot;
        else if (b == 1) meta[OFF_K1S + mypos[q]] = slot;
        else             meta[OFF_WSLOT + mypidx[q]] = slot;
    }
}

// ---------------------------------------------------------------------------
// Mono kernel: one block per tree, 1024 threads (32 groups / 16 waves).
// Phases: stage tables + ptr_pre + fn_pre + leaves | ptr rows | levels 1..5
// (lane=row, contiguous CSR gathers) | root + FF head.
// ---------------------------------------------------------------------------
__global__ __launch_bounds__(1024, 1) void tree_kernel(
    const int* __restrict__ meta,
    const int* __restrict__ tok_a, const int* __restrict__ tok_b,
    const int* __restrict__ ptr_time,
    const float* __restrict__ first_notes, const float* __restrict__ lstm_out,
    const float* __restrict__ embedding,
    const float* __restrict__ leaf_w1, const float* __restrict__ leaf_b1,
    const float* __restrict__ leaf_w2, const float* __restrict__ leaf_b2,
    const float* __restrict__ node_w, const float* __restrict__ node_b,
    const float* __restrict__ ptr_w, const float* __restrict__ ptr_b,
    const float* __restrict__ ff_w1, const float* __restrict__ ff_b1,
    const float* __restrict__ ff_w2, const float* __restrict__ ff_b2,
    const float* __restrict__ tail_w, const float* __restrict__ tail_b,
    float* __restrict__ ptrpre, float* __restrict__ h, float* __restrict__ out)
{
    __shared__ float eawN[VOCAB * 33];   // stride 33: 2-way bank conflicts only
    __shared__ float ebwN[VOCAB * 33];
    __shared__ float sfn[HID];
    __shared__ float red[32 * HID];

    int tree = blockIdx.x;
    int tid = threadIdx.x, grp = tid >> 5, lane = tid & 31;
    int gnbase = tree * N_PER;
    float* ht   = h + (size_t)gnbase * HID;
    float* ppre = ptrpre + (size_t)tree * T_LEN * HID;

    // --- embedding x node_w tables ---
    for (int idx = tid; idx < VOCAB * HID; idx += 1024) {
        int v = idx >> 5, d = idx & 31;
        float sa = 0.f, sb = 0.f;
        #pragma unroll
        for (int k = 0; k < EMBED; ++k) {
            float e = embedding[v * EMBED + k];
            sa += e * node_w[k * HID + d];
            sb += e * node_w[(EMBED + k) * HID + d];
        }
        eawN[v * 33 + d] = sa;
        ebwN[v * 33 + d] = sb;
    }
    // --- ptr_pre GEMV: lstm_out[tree] @ ptr_w[64:128] ---
    {
        const float* lo_base = lstm_out + (size_t)tree * T_LEN * LSTM_D;
        for (int r = grp; r < T_LEN; r += 32) {
            const float* lo = lo_base + r * LSTM_D;
            float v = 0.f;
            #pragma unroll
            for (int k = 0; k < LSTM_D; ++k) v += lo[k] * ptr_w[(NOTE + k) * HID + lane];
            ppre[r * HID + lane] = v;
        }
    }
    if (grp == 0) {
        const float* fn = first_notes + (size_t)tree * NOTE;
        float v = ptr_b[lane];
        #pragma unroll
        for (int k = 0; k < NOTE; ++k) v += fn[k] * ptr_w[k * HID + lane];
        sfn[lane] = v;
    }
    // --- leaf rows (lane=dim; only ~68 rows/tree) ---
    {
        int c0 = meta[MH_C0];
        const int* K0N = meta + OFF_K0N;
        const int* K0S = meta + OFF_K0S;
        float lb1 = leaf_b1[lane], lb2 = leaf_b2[lane];
        for (int j = grp; j < c0; j += 32) {
            int node = K0N[j], slot = K0S[j];
            int ta = tok_a[gnbase + node], tb = tok_b[gnbase + node];
            const float* ea = embedding + ta * EMBED;
            const float* eb = embedding + tb * EMBED;
            float hid = lb1;
            #pragma unroll
            for (int k = 0; k < EMBED; ++k) hid += ea[k] * leaf_w1[k * HID + lane];
            #pragma unroll
            for (int k = 0; k < EMBED; ++k) hid += eb[k] * leaf_w1[(EMBED + k) * HID + lane];
            float v = lb2;
            #pragma unroll
            for (int k = 0; k < HID; ++k) v += __shfl(hid, k, 32) * leaf_w2[k * HID + lane];
            ht[(size_t)slot * HID + lane] = v;
        }
    }
    __threadfence(); __syncthreads();

    // --- ptr rows: h = fn_pre + ptr_pre[tt] ---
    {
        int c1 = meta[MH_C1];
        const int* K1N = meta + OFF_K1N;
        const int* K1S = meta + OFF_K1S;
        float fnv = sfn[lane];
        for (int j = grp; j < c1; j += 32) {
            int node = K1N[j], slot = K1S[j];
            int tt = ptr_time[gnbase + node];
            ht[(size_t)slot * HID + lane] = fnv + ppre[tt * HID + lane];
        }
    }
    __threadfence(); __syncthreads();

    // --- levels 1..5: lane=row, contiguous CSR gather, register matvec ---
    const int* PL = meta + OFF_PLIST;
    const int* WS = meta + OFF_WSLOT;
    const int* CO = meta + OFF_COFF;
    for (int l = 0; l < 5; ++l) {
        int cnt = meta[MH_CNT + l], base = meta[MH_PBASE + l];
        for (int rr = tid; rr < cnt; rr += 1024) {
            int pidx = base + rr;
            int node = PL[pidx], wslot = WS[pidx];
            int e = CO[pidx], e1 = CO[pidx + 1];

            float4 cs[8];
            #pragma unroll
            for (int q = 0; q < 8; ++q) cs[q] = make_float4(0.f, 0.f, 0.f, 0.f);
            const float4* htv = (const float4*)ht;
            for (int c = e; c < e1; ++c) {
                const float4* row = htv + (size_t)c * 8;
                #pragma unroll
                for (int q = 0; q < 8; ++q) {
                    float4 x = row[q];
                    cs[q].x += x.x; cs[q].y += x.y; cs[q].z += x.z; cs[q].w += x.w;
                }
            }
            int ta = tok_a[gnbase + node], tb = tok_b[gnbase + node];
            const float4* nb4 = (const float4*)node_b;
            float4 v[8];
            #pragma unroll
            for (int q = 0; q < 8; ++q) {
                float4 nb = nb4[q];
                v[q].x = nb.x + eawN[ta * 33 + 4 * q + 0] + ebwN[tb * 33 + 4 * q + 0];
                v[q].y = nb.y + eawN[ta * 33 + 4 * q + 1] + ebwN[tb * 33 + 4 * q + 1];
                v[q].z = nb.z + eawN[ta * 33 + 4 * q + 2] + ebwN[tb * 33 + 4 * q + 2];
                v[q].w = nb.w + eawN[ta * 33 + 4 * q + 3] + ebwN[tb * 33 + 4 * q + 3];
            }
            auto fmarow = [&](float ck, const float* wrow) {
                const float4* w4 = (const float4*)wrow;
                #pragma unroll
                for (int p = 0; p < 8; ++p) {
                    float4 w = w4[p];
                    v[p].x += ck * w.x; v[p].y += ck * w.y;
                    v[p].z += ck * w.z; v[p].w += ck * w.w;
                }
            };
            #pragma unroll
            for (int q = 0; q < 8; ++q) {
                fmarow(cs[q].x, node_w + (2 * EMBED + 4 * q + 0) * HID);
                fmarow(cs[q].y, node_w + (2 * EMBED + 4 * q + 1) * HID);
                fmarow(cs[q].z, node_w + (2 * EMBED + 4 * q + 2) * HID);
                fmarow(cs[q].w, node_w + (2 * EMBED + 4 * q + 3) * HID);
            }
            float4* outr = (float4*)(ht + (size_t)wslot * HID);
            #pragma unroll
            for (int q = 0; q < 8; ++q) {
                float4 x = v[q];
                x.x = fmaxf(x.x, 0.f); x.y = fmaxf(x.y, 0.f);
                x.z = fmaxf(x.z, 0.f); x.w = fmaxf(x.w, 0.f);
                outr[q] = x;
            }
        }
        __threadfence(); __syncthreads();
    }

    // --- root: contiguous gather (range of last parent) + FF head ---
    {
        int P = meta[MH_P];
        int e = CO[P - 1], e1 = CO[P];
        float cssum = 0.f;
        for (int c = e + grp; c < e1; c += 32)
            cssum += ht[(size_t)c * HID + lane];
        red[grp * HID + lane] = cssum;
        __syncthreads();
        if (grp == 0) {
            float csum = 0.f;
            #pragma unroll
            for (int g = 0; g < 32; ++g) csum += red[g * HID + lane];
            int ta = tok_a[gnbase], tb = tok_b[gnbase];   // root = node 0
            float v = node_b[lane] + eawN[ta * 33 + lane] + ebwN[tb * 33 + lane];
            #pragma unroll
            for (int k = 0; k < HID; ++k)
                v += __shfl(csum, k, 32) * node_w[(2 * EMBED + k) * HID + lane];
            v = fmaxf(v, 0.f);

            float f1 = ff_b1[lane];
            #pragma unroll
            for (int k = 0; k < HID; ++k) f1 += __shfl(v, k, 32) * ff_w1[k * HID + lane];
            float f2 = ff_b2[lane];
            #pragma unroll
            for (int k = 0; k < HID; ++k) f2 += __shfl(f1, k, 32) * ff_w2[k * HID + lane];

            float c2 = f2 * tail_w[lane];
            #pragma unroll
            for (int off = 16; off > 0; off >>= 1) c2 += __shfl_down(c2, off, 32);
            if (lane == 0) out[tree] = c2 + tail_b[0];
        }
    }
}

extern "C" void kernel_launch(void* const* d_in, const int* in_sizes, int n_in,
                              void* d_out, int out_size, void* d_ws, size_t ws_size,
                              hipStream_t stream) {
    const int*   kind        = (const int*)d_in[0];
    const int*   height      = (const int*)d_in[1];
    const int*   parent      = (const int*)d_in[2];
    const int*   tok_a       = (const int*)d_in[3];
    const int*   tok_b       = (const int*)d_in[4];
    const int*   ptr_time    = (const int*)d_in[5];
    const float* first_notes = (const float*)d_in[6];
    const float* lstm_out    = (const float*)d_in[7];
    const float* embedding   = (const float*)d_in[8];
    const float* leaf_w1     = (const float*)d_in[9];
    const float* leaf_b1     = (const float*)d_in[10];
    const float* leaf_w2     = (const float*)d_in[11];
    const float* leaf_b2     = (const float*)d_in[12];
    const float* node_w      = (const float*)d_in[13];
    const float* node_b      = (const float*)d_in[14];
    const float* ptr_w       = (const float*)d_in[15];
    const float* ptr_b       = (const float*)d_in[16];
    const float* ff_w1       = (const float*)d_in[17];
    const float* ff_b1       = (const float*)d_in[18];
    const float* ff_w2       = (const float*)d_in[19];
    const float* ff_b2       = (const float*)d_in[20];
    const float* tail_w      = (const float*)d_in[21];
    const float* tail_b      = (const float*)d_in[22];

    char* ws = (char*)d_ws;
    int*   meta    = (int*)ws;
    float* ptrpre  = (float*)(ws + PTRPRE_OFF);
    float* h       = (float*)(ws + H_OFF);

    build_structure<<<1, 1024, 0, stream>>>(kind, height, parent, meta);

    tree_kernel<<<BATCH, 1024, 0, stream>>>(
        meta, tok_a, tok_b, ptr_time, first_notes, lstm_out, embedding,
        leaf_w1, leaf_b1, leaf_w2, leaf_b2, node_w, node_b, ptr_w, ptr_b,
        ff_w1, ff_b1, ff_w2, ff_b2, tail_w, tail_b,
        ptrpre, h, (float*)d_out);
}

// Round 6
// 402.188 us; speedup vs baseline: 3.0597x; 3.0597x over previous
//
#include <hip/hip_runtime.h>

// Problem constants (fixed by the reference's setup_inputs)
#define BATCH   256
#define N_PER   4096
#define EMBED   16
#define HID     32
#define NOTE    64
#define LSTM_D  64
#define T_LEN   128
#define VOCAB   200
#define HSTR    (BATCH * HID)       // floats per slot row-group (tree-inner layout)

// ---------------------------------------------------------------------------
// meta header (ints)
#define MH_C0    0     // kind-0 leaf count (per tree)
#define MH_C1    1     // kind-1 ptr count
#define MH_CNT   2     // [2..6] internal count at level 1..5
#define MH_P     7     // total parents (internal levels 1..5 + root)
#define MH_PBASE 8     // [8..12] pidx base of level 1..5
// arrays
#define OFF_K0N   64
#define OFF_K0S   (OFF_K0N + N_PER)
#define OFF_K1N   (OFF_K0S + N_PER)
#define OFF_K1S   (OFF_K1N + N_PER)
#define OFF_PLIST (OFF_K1S + N_PER)
#define OFF_WSLOT (OFF_PLIST + N_PER)
#define OFF_COFF  (OFF_WSLOT + N_PER)    // N_PER+1 entries
// float regions (byte offsets in ws)
#define EAW_OFF     (1024 * 1024)        // [VOCAB][HID]
#define EBW_OFF     (EAW_OFF + VOCAB * HID * 4)
#define FN_PRE_OFF  (1536 * 1024)        // [BATCH][HID]
#define ROOTSUM_OFF (1792 * 1024)        // [BATCH][HID]
#define PTRPRE_OFF  (2ull * 1024 * 1024) // [BATCH][T_LEN][HID]
#define H_OFF       (8ull * 1024 * 1024) // [N_PER slots][BATCH][HID]

#define RCHUNK 16

// ---------------------------------------------------------------------------
// Build (verified in R5): bucket nodes (k0, k1, levels 1..5, root) with stable
// packed-u64 scans; parents ordered by level; slot = CSR position in parent's
// children block => each level's child-slot range is contiguous.
// ---------------------------------------------------------------------------
__global__ __launch_bounds__(1024) void build_structure(
    const int* __restrict__ kind, const int* __restrict__ height,
    const int* __restrict__ parent, int* __restrict__ meta)
{
    __shared__ unsigned long long p64[1024];
    __shared__ int pint[1024];
    __shared__ int node2pidx[N_PER];   // 16 KB
    __shared__ int deg[N_PER];         // 16 KB
    __shared__ int sbases[8];
    __shared__ int stot[8];

    int t  = threadIdx.x;
    int i0 = 4 * t;

    int myb[4];
    #pragma unroll
    for (int q = 0; q < 4; ++q) {
        int i = i0 + q;
        int hgt = height[i];
        int b;
        if (hgt > 0) { b = 1 + hgt; if (b > 7) b = 7; }   // levels 1..5 -> 2..6, root -> 7
        else b = (kind[i] == 0) ? 0 : 1;
        myb[q] = b;
    }
    unsigned long long clo = 0, chi = 0;
    #pragma unroll
    for (int q = 0; q < 4; ++q) {
        int b = myb[q];
        if (b < 4) clo += 1ull << (16 * b);
        else       chi += 1ull << (16 * (b - 4));
    }
    p64[t] = clo; __syncthreads();
    for (int off = 1; off < 1024; off <<= 1) {
        unsigned long long v = (t >= off) ? p64[t - off] : 0ull; __syncthreads();
        p64[t] += v; __syncthreads();
    }
    unsigned long long inc_lo = p64[t];
    if (t == 1023) {
        stot[0] = (int)(inc_lo & 0xFFFF);         stot[1] = (int)((inc_lo >> 16) & 0xFFFF);
        stot[2] = (int)((inc_lo >> 32) & 0xFFFF); stot[3] = (int)((inc_lo >> 48) & 0xFFFF);
    }
    __syncthreads();
    p64[t] = chi; __syncthreads();
    for (int off = 1; off < 1024; off <<= 1) {
        unsigned long long v = (t >= off) ? p64[t - off] : 0ull; __syncthreads();
        p64[t] += v; __syncthreads();
    }
    unsigned long long inc_hi = p64[t];
    if (t == 1023) {
        stot[4] = (int)(inc_hi & 0xFFFF);         stot[5] = (int)((inc_hi >> 16) & 0xFFFF);
        stot[6] = (int)((inc_hi >> 32) & 0xFFFF); stot[7] = (int)((inc_hi >> 48) & 0xFFFF);
    }
    __syncthreads();
    if (t == 0) {
        int s = 0;
        for (int b = 0; b < 8; ++b) { sbases[b] = s; s += stot[b]; }
        meta[MH_C0] = stot[0];
        meta[MH_C1] = stot[1];
        for (int l = 0; l < 5; ++l) meta[MH_CNT + l]   = stot[2 + l];
        for (int l = 0; l < 5; ++l) meta[MH_PBASE + l] = sbases[2 + l] - sbases[2];
        meta[MH_P] = (sbases[7] - sbases[2]) + stot[7];
    }
    __syncthreads();

    unsigned long long exlo = inc_lo - clo, exhi = inc_hi - chi;
    int mypos[4], mypidx[4];
    #pragma unroll
    for (int q = 0; q < 4; ++q) {
        int i = i0 + q, b = myb[q];
        int pos;
        if (b < 4) { pos = (int)((exlo >> (16 * b)) & 0xFFFF); exlo += 1ull << (16 * b); }
        else       { pos = (int)((exhi >> (16 * (b - 4))) & 0xFFFF); exhi += 1ull << (16 * (b - 4)); }
        mypos[q] = pos;
        int pidx = -1;
        if (b == 0)      meta[OFF_K0N + pos] = i;
        else if (b == 1) meta[OFF_K1N + pos] = i;
        else {
            pidx = (sbases[b] - sbases[2]) + pos;
            meta[OFF_PLIST + pidx] = i;
            node2pidx[i] = pidx;
        }
        mypidx[q] = pidx;
    }
    #pragma unroll
    for (int q = 0; q < 4; ++q) deg[i0 + q] = 0;
    __syncthreads();

    int par[4];
    #pragma unroll
    for (int q = 0; q < 4; ++q) {
        int i = i0 + q; par[q] = parent[i];
        if (i != 0) atomicAdd(&deg[node2pidx[par[q]]], 1);
    }
    __syncthreads();

    int d0 = deg[i0], d1 = deg[i0 + 1], d2 = deg[i0 + 2], d3 = deg[i0 + 3];
    int s4 = d0 + d1 + d2 + d3;
    pint[t] = s4; __syncthreads();
    for (int off = 1; off < 1024; off <<= 1) {
        int v = (t >= off) ? pint[t - off] : 0; __syncthreads();
        pint[t] += v; __syncthreads();
    }
    int ex = pint[t] - s4;
    int o0 = ex, o1 = ex + d0, o2 = o1 + d1, o3 = o2 + d2;
    deg[i0] = o0; deg[i0 + 1] = o1; deg[i0 + 2] = o2; deg[i0 + 3] = o3;
    meta[OFF_COFF + i0]     = o0;
    meta[OFF_COFF + i0 + 1] = o1;
    meta[OFF_COFF + i0 + 2] = o2;
    meta[OFF_COFF + i0 + 3] = o3;
    if (t == 1023) meta[OFF_COFF + N_PER] = o3 + d3;
    __syncthreads();

    #pragma unroll
    for (int q = 0; q < 4; ++q) {
        int i = i0 + q; if (i == 0) continue;
        int slot = atomicAdd(&deg[node2pidx[par[q]]], 1);
        int b = myb[q];
        if (b == 0)      meta[OFF_K0S + mypos[q]] = slot;
        else if (b == 1) meta[OFF_K1S + mypos[q]] = slot;
        else             meta[OFF_WSLOT + mypidx[q]] = slot;
    }
}

// ---------------------------------------------------------------------------
// Prep: eaw/ebw tables, fn_pre, ptr_pre GEMV, leaf h (tree-inner coalesced).
// ---------------------------------------------------------------------------
__global__ __launch_bounds__(256) void prep_kernel(
    const int* __restrict__ meta,
    const int* __restrict__ tok_a, const int* __restrict__ tok_b,
    const float* __restrict__ first_notes, const float* __restrict__ lstm_out,
    const float* __restrict__ embedding,
    const float* __restrict__ leaf_w1, const float* __restrict__ leaf_b1,
    const float* __restrict__ leaf_w2, const float* __restrict__ leaf_b2,
    const float* __restrict__ node_w,
    const float* __restrict__ ptr_w, const float* __restrict__ ptr_b,
    float* __restrict__ eaw_g, float* __restrict__ ebw_g,
    float* __restrict__ fn_pre, float* __restrict__ ptr_pre,
    float* __restrict__ h)
{
    int tid  = blockIdx.x * blockDim.x + threadIdx.x;
    int nthr = gridDim.x * blockDim.x;
    int lane = threadIdx.x & 31;
    int gid  = tid >> 5;
    int ngr  = nthr >> 5;

    // --- A: eaw/ebw tables: emb[v] @ node_w[:16] and @ node_w[16:32] ---
    for (int idx = tid; idx < VOCAB * HID; idx += nthr) {
        int v = idx >> 5, d = idx & 31;
        float sa = 0.f, sb = 0.f;
        #pragma unroll
        for (int k = 0; k < EMBED; ++k) {
            float e = embedding[v * EMBED + k];
            sa += e * node_w[k * HID + d];
            sb += e * node_w[(EMBED + k) * HID + d];
        }
        eaw_g[idx] = sa;
        ebw_g[idx] = sb;
    }

    // --- B: fn_pre[tree] = ptr_b + first_notes[tree] @ ptr_w[0:64] ---
    for (int r = gid; r < BATCH; r += ngr) {
        const float* fn = first_notes + (size_t)r * NOTE;
        float v = ptr_b[lane];
        #pragma unroll
        for (int k = 0; k < NOTE; ++k) v += fn[k] * ptr_w[k * HID + lane];
        fn_pre[r * HID + lane] = v;
    }

    // --- C: ptr_pre[r] = lstm_out_flat[r] @ ptr_w[64:128] ---
    for (int r = gid; r < BATCH * T_LEN; r += ngr) {
        const float* lo = lstm_out + (size_t)r * LSTM_D;
        float v = 0.f;
        #pragma unroll
        for (int k = 0; k < LSTM_D; ++k) v += lo[k] * ptr_w[(NOTE + k) * HID + lane];
        ptr_pre[r * HID + lane] = v;
    }

    // --- D: leaf rows, items = j*BATCH + tree (tree-inner) ---
    {
        int c0 = meta[MH_C0];
        const int* K0N = meta + OFF_K0N;
        const int* K0S = meta + OFF_K0S;
        float w1a[EMBED], w1b[EMBED], w2c[HID];
        #pragma unroll
        for (int k = 0; k < EMBED; ++k) {
            w1a[k] = leaf_w1[k * HID + lane];
            w1b[k] = leaf_w1[(EMBED + k) * HID + lane];
        }
        #pragma unroll
        for (int k = 0; k < HID; ++k) w2c[k] = leaf_w2[k * HID + lane];
        float b1 = leaf_b1[lane], b2 = leaf_b2[lane];

        int tot = c0 * BATCH;
        for (int i = gid; i < tot; i += ngr) {
            int j = i >> 8, tree = i & 255;
            int node = K0N[j], slot = K0S[j];
            int gn = tree * N_PER + node;
            const float* ea = embedding + tok_a[gn] * EMBED;
            const float* eb = embedding + tok_b[gn] * EMBED;
            float hid = b1;
            #pragma unroll
            for (int k = 0; k < EMBED; ++k) hid += ea[k] * w1a[k];
            #pragma unroll
            for (int k = 0; k < EMBED; ++k) hid += eb[k] * w1b[k];
            float v = b2;
            #pragma unroll
            for (int k = 0; k < HID; ++k) v += __shfl(hid, k, 32) * w2c[k];
            h[(size_t)slot * HSTR + tree * HID + lane] = v;
        }
    }
}

// ---------------------------------------------------------------------------
// Ptr rows: h[slot][tree] = fn_pre[tree] + ptr_pre[tree][tt]
// ---------------------------------------------------------------------------
__global__ __launch_bounds__(256) void ptr_kernel(
    const int* __restrict__ meta, const int* __restrict__ ptr_time,
    const float* __restrict__ fn_pre, const float* __restrict__ ptr_pre,
    float* __restrict__ h)
{
    int c1 = meta[MH_C1];
    const int* K1N = meta + OFF_K1N;
    const int* K1S = meta + OFF_K1S;
    int lane = threadIdx.x & 31;
    int gid  = (blockIdx.x * blockDim.x + threadIdx.x) >> 5;
    int ngr  = (gridDim.x * blockDim.x) >> 5;

    int tot = c1 * BATCH;
    for (int i = gid; i < tot; i += ngr) {
        int j = i >> 8, tree = i & 255;
        int node = K1N[j], slot = K1S[j];
        int tt = ptr_time[tree * N_PER + node];
        float v = fn_pre[tree * HID + lane]
                + ptr_pre[((size_t)tree * T_LEN + tt) * HID + lane];
        h[(size_t)slot * HSTR + tree * HID + lane] = v;
    }
}

// ---------------------------------------------------------------------------
// Level pass (lvl = 0..4 for heights 1..5): for parents at this level,
//   h[wslot][tree] = relu(node_b + eaw[ta] + ebw[tb] + csum @ node_w[32:64])
// Children of the level form a contiguous slot range -> streaming reads.
// Work item = (tree-chunk, parent, tree-in-chunk) for L2 tok locality.
// ---------------------------------------------------------------------------
__global__ __launch_bounds__(256) void level_kernel(
    const int* __restrict__ meta,
    const int* __restrict__ tok_a, const int* __restrict__ tok_b,
    const float* __restrict__ eaw_g, const float* __restrict__ ebw_g,
    const float* __restrict__ node_w, const float* __restrict__ node_b,
    float* __restrict__ h, int lvl)
{
    int cnt = meta[MH_CNT + lvl];
    int pb  = meta[MH_PBASE + lvl];
    const int* PL = meta + OFF_PLIST;
    const int* WS = meta + OFF_WSLOT;
    const int* CO = meta + OFF_COFF;

    int lane = threadIdx.x & 31;
    int gid  = (blockIdx.x * blockDim.x + threadIdx.x) >> 5;
    int ngr  = (gridDim.x * blockDim.x) >> 5;

    float wc[HID];
    #pragma unroll
    for (int k = 0; k < HID; ++k) wc[k] = node_w[(2 * EMBED + k) * HID + lane];
    float nb = node_b[lane];

    int perchunk = cnt << 5;             // parents * 32 trees
    int tot = cnt * BATCH;
    for (int i = gid; i < tot; i += ngr) {
        int tchunk = i / perchunk;
        int r      = i - tchunk * perchunk;
        int rr     = r >> 5;
        int tree   = (tchunk << 5) + (r & 31);
        int pidx = pb + rr;
        int node = PL[pidx], wslot = WS[pidx];
        int e = CO[pidx], e1 = CO[pidx + 1];

        const float* hb = h + (size_t)tree * HID + lane;
        float csum = 0.f;
        for (int c = e; c < e1; ++c) csum += hb[(size_t)c * HSTR];

        int gn = tree * N_PER + node;
        int ta = tok_a[gn], tb = tok_b[gn];
        float v = nb + eaw_g[ta * HID + lane] + ebw_g[tb * HID + lane];
        #pragma unroll
        for (int k = 0; k < HID; ++k) v += __shfl(csum, k, 32) * wc[k];
        v = fmaxf(v, 0.f);
        h[(size_t)wslot * HSTR + tree * HID + lane] = v;
    }
}

// ---------------------------------------------------------------------------
// Root gather: chunked coalesced partial sums -> atomicAdd rootsum[tree][hid]
// ---------------------------------------------------------------------------
__global__ __launch_bounds__(256) void root_gather_kernel(
    const int* __restrict__ meta, const float* __restrict__ h,
    float* __restrict__ rootsum)
{
    const int* CO = meta + OFF_COFF;
    int P = meta[MH_P];
    int e = CO[P - 1], e1 = CO[P];
    int n = e1 - e;
    int per = (n + RCHUNK - 1) / RCHUNK;

    int t = blockIdx.x * blockDim.x + threadIdx.x;   // RCHUNK*BATCH*HID threads
    int lane  = t & 31;
    int tree  = (t >> 5) & 255;
    int chunk = t >> 13;
    if (chunk >= RCHUNK) return;

    int s  = e + chunk * per;
    int en = s + per; if (en > e1) en = e1;
    if (s >= en) return;
    float sum = 0.f;
    for (int c = s; c < en; ++c)
        sum += h[(size_t)c * HSTR + tree * HID + lane];
    atomicAdd(&rootsum[tree * HID + lane], sum);
}

// ---------------------------------------------------------------------------
// Final: finish root h, FF head -> out[tree]
// ---------------------------------------------------------------------------
__global__ __launch_bounds__(256) void final_kernel(
    const int* __restrict__ meta,
    const int* __restrict__ tok_a, const int* __restrict__ tok_b,
    const float* __restrict__ eaw_g, const float* __restrict__ ebw_g,
    const float* __restrict__ rootsum,
    const float* __restrict__ node_w, const float* __restrict__ node_b,
    const float* __restrict__ ff_w1, const float* __restrict__ ff_b1,
    const float* __restrict__ ff_w2, const float* __restrict__ ff_b2,
    const float* __restrict__ tail_w, const float* __restrict__ tail_b,
    float* __restrict__ out)
{
    int tree = (blockIdx.x * blockDim.x + threadIdx.x) >> 5;
    int lane = threadIdx.x & 31;
    if (tree >= BATCH) return;

    float csum = rootsum[tree * HID + lane];
    int gn = tree * N_PER;   // root = node 0
    int ta = tok_a[gn], tb = tok_b[gn];
    float v = node_b[lane] + eaw_g[ta * HID + lane] + ebw_g[tb * HID + lane];
    #pragma unroll
    for (int k = 0; k < HID; ++k)
        v += __shfl(csum, k, 32) * node_w[(2 * EMBED + k) * HID + lane];
    v = fmaxf(v, 0.f);

    float f1 = ff_b1[lane];
    #pragma unroll
    for (int k = 0; k < HID; ++k) f1 += __shfl(v, k, 32) * ff_w1[k * HID + lane];
    float f2 = ff_b2[lane];
    #pragma unroll
    for (int k = 0; k < HID; ++k) f2 += __shfl(f1, k, 32) * ff_w2[k * HID + lane];

    float c2 = f2 * tail_w[lane];
    #pragma unroll
    for (int off = 16; off > 0; off >>= 1) c2 += __shfl_down(c2, off, 32);
    if (lane == 0) out[tree] = c2 + tail_b[0];
}

extern "C" void kernel_launch(void* const* d_in, const int* in_sizes, int n_in,
                              void* d_out, int out_size, void* d_ws, size_t ws_size,
                              hipStream_t stream) {
    const int*   kind        = (const int*)d_in[0];
    const int*   height      = (const int*)d_in[1];
    const int*   parent      = (const int*)d_in[2];
    const int*   tok_a       = (const int*)d_in[3];
    const int*   tok_b       = (const int*)d_in[4];
    const int*   ptr_time    = (const int*)d_in[5];
    const float* first_notes = (const float*)d_in[6];
    const float* lstm_out    = (const float*)d_in[7];
    const float* embedding   = (const float*)d_in[8];
    const float* leaf_w1     = (const float*)d_in[9];
    const float* leaf_b1     = (const float*)d_in[10];
    const float* leaf_w2     = (const float*)d_in[11];
    const float* leaf_b2     = (const float*)d_in[12];
    const float* node_w      = (const float*)d_in[13];
    const float* node_b      = (const float*)d_in[14];
    const float* ptr_w       = (const float*)d_in[15];
    const float* ptr_b       = (const float*)d_in[16];
    const float* ff_w1       = (const float*)d_in[17];
    const float* ff_b1       = (const float*)d_in[18];
    const float* ff_w2       = (const float*)d_in[19];
    const float* ff_b2       = (const float*)d_in[20];
    const float* tail_w      = (const float*)d_in[21];
    const float* tail_b      = (const float*)d_in[22];

    char* ws = (char*)d_ws;
    int*   meta    = (int*)ws;
    float* eaw_g   = (float*)(ws + EAW_OFF);
    float* ebw_g   = (float*)(ws + EBW_OFF);
    float* fn_pre  = (float*)(ws + FN_PRE_OFF);
    float* rootsum = (float*)(ws + ROOTSUM_OFF);
    float* ptr_pre = (float*)(ws + PTRPRE_OFF);
    float* h       = (float*)(ws + H_OFF);

    hipMemsetAsync(rootsum, 0, BATCH * HID * sizeof(float), stream);

    build_structure<<<1, 1024, 0, stream>>>(kind, height, parent, meta);

    prep_kernel<<<2048, 256, 0, stream>>>(
        meta, tok_a, tok_b, first_notes, lstm_out, embedding,
        leaf_w1, leaf_b1, leaf_w2, leaf_b2, node_w, ptr_w, ptr_b,
        eaw_g, ebw_g, fn_pre, ptr_pre, h);

    ptr_kernel<<<2048, 256, 0, stream>>>(meta, ptr_time, fn_pre, ptr_pre, h);

    for (int lvl = 0; lvl < 5; ++lvl) {
        level_kernel<<<4096, 256, 0, stream>>>(
            meta, tok_a, tok_b, eaw_g, ebw_g, node_w, node_b, h, lvl);
    }

    root_gather_kernel<<<(RCHUNK * BATCH * HID) / 256, 256, 0, stream>>>(
        meta, h, rootsum);

    final_kernel<<<32, 256, 0, stream>>>(
        meta, tok_a, tok_b, eaw_g, ebw_g, rootsum, node_w, node_b,
        ff_w1, ff_b1, ff_w2, ff_b2, tail_w, tail_b, (float*)d_out);
}